// Round 18
// baseline (76.450 us; speedup 1.0000x reference)
//
#include <hip/hip_runtime.h>
#include <math.h>

#define Bn 64
#define Pn 8732
#define Cn 21
#define NMAXn 50
#define PX 35  // ceil(Pn/256)

// ---------------- DPP wave64 reduces (VALU pipe, not LDS) -------------------
template <int C>
__device__ __forceinline__ float dppf(float x) {
    return __int_as_float(__builtin_amdgcn_update_dpp(0, __float_as_int(x), C, 0xf, 0xf, true));
}
template <int C>
__device__ __forceinline__ int dppi(int x) {
    return __builtin_amdgcn_update_dpp(0, x, C, 0xf, 0xf, true);
}
__device__ __forceinline__ float wave_sum_f(float x) {
    x += dppf<0x111>(x); x += dppf<0x112>(x); x += dppf<0x114>(x);
    x += dppf<0x118>(x); x += dppf<0x142>(x); x += dppf<0x143>(x);
    return x;  // lane 63
}
__device__ __forceinline__ int wave_sum_i(int x) {
    x += dppi<0x111>(x); x += dppi<0x112>(x); x += dppi<0x114>(x);
    x += dppi<0x118>(x); x += dppi<0x142>(x); x += dppi<0x143>(x);
    return x;  // lane 63
}

__device__ __forceinline__ float smoothl1_enc(const float4 l, const float4 pr,
                                              float gx0, float gy0, float gx1, float gy1) {
    const float tx = ((gx0 + gx1) * 0.5f - pr.x) / (0.1f * pr.z);
    const float ty = ((gy0 + gy1) * 0.5f - pr.y) / (0.1f * pr.w);
    const float tw = __logf((gx1 - gx0) / pr.z) * 5.0f;  // /0.2
    const float th = __logf((gy1 - gy0) / pr.w) * 5.0f;
    float s = 0.0f, d;
    d = fabsf(l.x - tx); s += (d < 1.0f) ? 0.5f * d * d : d - 0.5f;
    d = fabsf(l.y - ty); s += (d < 1.0f) ? 0.5f * d * d : d - 0.5f;
    d = fabsf(l.z - tw); s += (d < 1.0f) ? 0.5f * d * d : d - 0.5f;
    d = fabsf(l.w - th); s += (d < 1.0f) ? 0.5f * d * d : d - 0.5f;
    return s;
}

// IoU numerator/denominator (no divide). All >= 0.
#define IOU_IU(gx0, gy0, gx1, gy1, qx0, qy0, qx1, qy1, qarea, I, U)            \
    {                                                                          \
        const float lx = fmaxf(gx0, qx0), ly = fmaxf(gy0, qy0);                \
        const float rx = fminf(gx1, qx1), ry = fminf(gy1, qy1);                \
        const float w = fmaxf(rx - lx, 0.0f), h = fmaxf(ry - ly, 0.0f);        \
        I = w * h;                                                             \
        U = (gx1 - gx0) * (gy1 - gy0) + qarea - I;                             \
    }

// ---------------------------------------------------------------------------
// K1, two roles in one dispatch (R16-identical). Division-free cross-mult
// comparator, dual trackers.
// ---------------------------------------------------------------------------
__global__ __launch_bounds__(256) void k_fused(const float* __restrict__ conf,
                                               const float* __restrict__ loc,
                                               const float* __restrict__ priors,
                                               const float* __restrict__ labels,
                                               const int* __restrict__ objc,
                                               float* __restrict__ lc,
                                               float* __restrict__ part_loc,
                                               float* __restrict__ part_nll,
                                               int* __restrict__ part_np,
                                               int* __restrict__ sbp_g) {
    const int bx = blockIdx.x;
    const int tid = threadIdx.x;
    const int lane = tid & 63, wid = tid >> 6;

    __shared__ float sconf[256 * Cn];  // 21504 B (role A)
    __shared__ float lab[NMAXn * 5];
    __shared__ float rl[4], rn[4];
    __shared__ int rp[4];
    __shared__ float wkI[4], wkU[4];   // role B
    __shared__ int wkP[4];

    if (bx < Bn * PX) {
        // ================= Role A: match + main =================
        const int b = bx / PX;
        const int px = bx % PX;
        const int p0 = px * 256;
        const int rows = min(256, Pn - p0);
        const int cnt = objc[b];                  // uniform -> scalar
        const float* lb = labels + b * NMAXn * 5;

        const float4* src = reinterpret_cast<const float4*>(conf + ((size_t)b * Pn + p0) * Cn);
        const int n4 = rows * Cn / 4;  // rows*21 divisible by 4 for rows in {256,28}
        for (int i = tid; i < n4; i += 256) reinterpret_cast<float4*>(sconf)[i] = src[i];
        for (int i = tid; i < NMAXn * 5; i += 256) lab[i] = labels[b * NMAXn * 5 + i];

        const int p = p0 + tid;
        const int pcl = (p < Pn) ? p : (Pn - 1);
        const float4 pr = reinterpret_cast<const float4*>(priors)[pcl];
        const float px0 = pr.x - 0.5f * pr.z, py0 = pr.y - 0.5f * pr.w;
        const float px1 = pr.x + 0.5f * pr.z, py1 = pr.y + 0.5f * pr.w;
        const float parea = (px1 - px0) * (py1 - py0);
        float bI0 = 0.0f, bU0 = 1.0f, bI1 = 0.0f, bU1 = 1.0f;
        int bx0 = 0, bx1 = 0;
        int n = 0;
        for (; n + 1 < cnt; n += 2) {
            float I0, U0, I1, U1;
            IOU_IU(lb[n * 5 + 0], lb[n * 5 + 1], lb[n * 5 + 2], lb[n * 5 + 3],
                   px0, py0, px1, py1, parea, I0, U0);
            IOU_IU(lb[(n + 1) * 5 + 0], lb[(n + 1) * 5 + 1], lb[(n + 1) * 5 + 2],
                   lb[(n + 1) * 5 + 3], px0, py0, px1, py1, parea, I1, U1);
            if (I0 * bU0 > bI0 * U0) { bI0 = I0; bU0 = U0; bx0 = n; }
            if (I1 * bU1 > bI1 * U1) { bI1 = I1; bU1 = U1; bx1 = n + 1; }
        }
        if (n < cnt) {  // odd tail -> t0
            float I0, U0;
            IOU_IU(lb[n * 5 + 0], lb[n * 5 + 1], lb[n * 5 + 2], lb[n * 5 + 3],
                   px0, py0, px1, py1, parea, I0, U0);
            if (I0 * bU0 > bI0 * U0) { bI0 = I0; bU0 = U0; bx0 = n; }
        }
        {   // combine: product tie -> min index (global first-occurrence)
            const float a = bI1 * bU0, c = bI0 * bU1;
            if (a > c || (a == c && bx1 < bx0)) { bI0 = bI1; bU0 = bU1; bx0 = bx1; }
        }
        __syncthreads();  // sconf, lab ready

        float my_loc = 0.0f, my_nll = 0.0f;
        int my_np = 0;
        if (tid < rows) {
            const size_t gi = (size_t)b * Pn + p;
            const int ct = (2.0f * bI0 >= bU0) ? ((int)lab[bx0 * 5 + 4] + 1) : 0;
            const float* row = sconf + tid * Cn;  // stride 21: odd -> conflict-benign
            float m = row[0];
#pragma unroll
            for (int j = 1; j < Cn; ++j) m = fmaxf(m, row[j]);
            float s2 = 0.0f;
#pragma unroll
            for (int j = 0; j < Cn; ++j) s2 += __expf(row[j] - m);
            const float nll = __logf(s2) + m - row[ct];
            if (ct > 0) {
                lc[gi] = 0.0f;
                my_np = 1;
                my_nll = nll;
                const float4 l = reinterpret_cast<const float4*>(loc)[gi];
                my_loc = smoothl1_enc(l, pr, lab[bx0 * 5 + 0], lab[bx0 * 5 + 1],
                                      lab[bx0 * 5 + 2], lab[bx0 * 5 + 3]);
            } else {
                lc[gi] = nll;
            }
        }
        my_loc = wave_sum_f(my_loc);
        my_nll = wave_sum_f(my_nll);
        my_np = wave_sum_i(my_np);
        if (lane == 63) { rl[wid] = my_loc; rn[wid] = my_nll; rp[wid] = my_np; }
        __syncthreads();
        if (tid == 0) {
            const int g = b * PX + px;
            part_loc[g] = rl[0] + rl[1] + rl[2] + rl[3];
            part_nll[g] = rn[0] + rn[1] + rn[2] + rn[3];
            part_np[g] = rp[0] + rp[1] + rp[2] + rp[3];
        }
    } else {
        // ================= Role B: block-per-GT best-prior =================
        const int idx = bx - Bn * PX;
        const int b = idx / NMAXn;
        const int n = idx % NMAXn;
        if (n >= objc[b]) return;  // uniform per block
        const float* lbp = labels + (b * NMAXn + n) * 5;
        const float gx0 = lbp[0], gy0 = lbp[1], gx1 = lbp[2], gy1 = lbp[3];
        float bI0, bU0, bI1, bU1;
        int bp0, bp1;
        {
            const float4 pr = reinterpret_cast<const float4*>(priors)[tid];
            const float qx0 = pr.x - 0.5f * pr.z, qy0 = pr.y - 0.5f * pr.w;
            const float qx1 = pr.x + 0.5f * pr.z, qy1 = pr.y + 0.5f * pr.w;
            IOU_IU(gx0, gy0, gx1, gy1, qx0, qy0, qx1, qy1,
                   (qx1 - qx0) * (qy1 - qy0), bI0, bU0);
            bp0 = tid;
        }
        {
            const float4 pr = reinterpret_cast<const float4*>(priors)[tid + 256];
            const float qx0 = pr.x - 0.5f * pr.z, qy0 = pr.y - 0.5f * pr.w;
            const float qx1 = pr.x + 0.5f * pr.z, qy1 = pr.y + 0.5f * pr.w;
            IOU_IU(gx0, gy0, gx1, gy1, qx0, qy0, qx1, qy1,
                   (qx1 - qx0) * (qy1 - qy0), bI1, bU1);
            bp1 = tid + 256;
        }
        int j = 2;
        for (; j + 1 < PX; j += 2) {  // j <= 33: p <= 8703 < Pn, no guard
            const int pA = tid + 256 * j, pB = pA + 256;
            float IA, UA, IB, UB;
            {
                const float4 pr = reinterpret_cast<const float4*>(priors)[pA];
                const float qx0 = pr.x - 0.5f * pr.z, qy0 = pr.y - 0.5f * pr.w;
                const float qx1 = pr.x + 0.5f * pr.z, qy1 = pr.y + 0.5f * pr.w;
                IOU_IU(gx0, gy0, gx1, gy1, qx0, qy0, qx1, qy1,
                       (qx1 - qx0) * (qy1 - qy0), IA, UA);
            }
            {
                const float4 pr = reinterpret_cast<const float4*>(priors)[pB];
                const float qx0 = pr.x - 0.5f * pr.z, qy0 = pr.y - 0.5f * pr.w;
                const float qx1 = pr.x + 0.5f * pr.z, qy1 = pr.y + 0.5f * pr.w;
                IOU_IU(gx0, gy0, gx1, gy1, qx0, qy0, qx1, qy1,
                       (qx1 - qx0) * (qy1 - qy0), IB, UB);
            }
            if (IA * bU0 > bI0 * UA) { bI0 = IA; bU0 = UA; bp0 = pA; }
            if (IB * bU1 > bI1 * UB) { bI1 = IB; bU1 = UB; bp1 = pB; }
        }
        {   // tail j = 34 (guarded)
            const int pA = tid + 256 * 34;
            if (pA < Pn) {
                const float4 pr = reinterpret_cast<const float4*>(priors)[pA];
                const float qx0 = pr.x - 0.5f * pr.z, qy0 = pr.y - 0.5f * pr.w;
                const float qx1 = pr.x + 0.5f * pr.z, qy1 = pr.y + 0.5f * pr.w;
                float IA, UA;
                IOU_IU(gx0, gy0, gx1, gy1, qx0, qy0, qx1, qy1,
                       (qx1 - qx0) * (qy1 - qy0), IA, UA);
                if (IA * bU0 > bI0 * UA) { bI0 = IA; bU0 = UA; bp0 = pA; }
            }
        }
        {   // combine trackers: product tie -> min p
            const float a = bI1 * bU0, c = bI0 * bU1;
            if (a > c || (a == c && bp1 < bp0)) { bI0 = bI1; bU0 = bU1; bp0 = bp1; }
        }
        for (int off = 32; off > 0; off >>= 1) {
            const float oI = __shfl_down(bI0, off);
            const float oU = __shfl_down(bU0, off);
            const int op = __shfl_down(bp0, off);
            const float a = oI * bU0, c = bI0 * oU;
            if (a > c || (a == c && op < bp0)) { bI0 = oI; bU0 = oU; bp0 = op; }
        }
        if (lane == 0) { wkI[wid] = bI0; wkU[wid] = bU0; wkP[wid] = bp0; }
        __syncthreads();
        if (tid == 0) {
            float cI = wkI[0], cU = wkU[0];
            int cp = wkP[0];
#pragma unroll
            for (int w = 1; w < 4; ++w) {
                const float a = wkI[w] * cU, c = cI * wkU[w];
                if (a > c || (a == c && wkP[w] < cp)) { cI = wkI[w]; cU = wkU[w]; cp = wkP[w]; }
            }
            sbp_g[b * NMAXn + n] = cp;
        }
    }
}

// ---------------------------------------------------------------------------
// K2 fixup (one wave per batch, separate kernel — R16-identical).
// ---------------------------------------------------------------------------
__global__ __launch_bounds__(64) void k_fix(const float* __restrict__ conf,
                                            const float* __restrict__ loc,
                                            const float* __restrict__ priors,
                                            const float* __restrict__ labels,
                                            const int* __restrict__ objc,
                                            const int* __restrict__ sbp_g,
                                            float* __restrict__ lc,
                                            int* __restrict__ fix_np,
                                            float* __restrict__ fix_nll,
                                            float* __restrict__ fix_loc,
                                            int* __restrict__ done) {
    __shared__ int sbp[NMAXn];
    __shared__ float lab[NMAXn * 5];
    const int b = blockIdx.x;
    const int tid = threadIdx.x;  // one wave
    if (b == 0 && tid == 0) *done = 0;
    const int cnt = objc[b];
    for (int i = tid; i < NMAXn * 5; i += 64) lab[i] = labels[b * NMAXn * 5 + i];
    if (tid < cnt) sbp[tid] = sbp_g[b * NMAXn + tid];
    __syncthreads();
    bool win = false;
    if (tid < cnt) {
        const int myp = sbp[tid];
        win = true;
        for (int n2 = tid + 1; n2 < cnt; ++n2) win = win && (sbp[n2] != myp);  // last n wins
    }
    float dnll = 0.0f, dloc = 0.0f;
    int dnp = 0;
    if (win) {
        const int pp = sbp[tid];
        const float4 prf = reinterpret_cast<const float4*>(priors)[pp];
        const float qx0 = prf.x - 0.5f * prf.z, qy0 = prf.y - 0.5f * prf.w;
        const float qx1 = prf.x + 0.5f * prf.z, qy1 = prf.y + 0.5f * prf.w;
        const float qarea = (qx1 - qx0) * (qy1 - qy0);
        float bI = 0.0f, bU = 1.0f;
        int bidx2 = 0;
        for (int n2 = 0; n2 < cnt; ++n2) {  // sequential == dual-tracker combined order
            float I, U;
            IOU_IU(lab[n2 * 5 + 0], lab[n2 * 5 + 1], lab[n2 * 5 + 2],
                   lab[n2 * 5 + 3], qx0, qy0, qx1, qy1, qarea, I, U);
            if (I * bU > bI * U) { bI = I; bU = U; bidx2 = n2; }
        }
        const float* rowg = conf + ((size_t)b * Pn + pp) * Cn;
        float m2 = rowg[0];
#pragma unroll
        for (int j = 1; j < Cn; ++j) m2 = fmaxf(m2, rowg[j]);
        float ss = 0.0f;
#pragma unroll
        for (int j = 0; j < Cn; ++j) ss += __expf(rowg[j] - m2);
        const float lse = __logf(ss) + m2;
        const int ctn = (int)lab[tid * 5 + 4] + 1;
        const float4 lv = reinterpret_cast<const float4*>(loc)[(size_t)b * Pn + pp];
        dnll = lse - rowg[ctn];
        dloc = smoothl1_enc(lv, prf, lab[tid * 5 + 0], lab[tid * 5 + 1],
                            lab[tid * 5 + 2], lab[tid * 5 + 3]);
        dnp = 1;
        if (2.0f * bI >= bU) {  // old was positive: subtract its old contribution
            const int cto = (int)lab[bidx2 * 5 + 4] + 1;
            dnll -= (lse - rowg[cto]);
            dloc -= smoothl1_enc(lv, prf, lab[bidx2 * 5 + 0], lab[bidx2 * 5 + 1],
                                 lab[bidx2 * 5 + 2], lab[bidx2 * 5 + 3]);
            dnp = 0;
        }
        lc[(size_t)b * Pn + pp] = 0.0f;  // forced => positive => not a mining candidate
    }
    dnll = wave_sum_f(dnll);
    dloc = wave_sum_f(dloc);
    dnp = wave_sum_i(dnp);
    if (tid == 63) {
        fix_nll[b] = dnll;
        fix_loc[b] = dloc;
        fix_np[b] = dnp;
    }
}

// ---------------------------------------------------------------------------
// K3: per-batch hard-negative top-k sum. 256 threads x 12 float4 in registers.
// 8-WAY RADIX BISECTION: 10 iterations over 3-bit fields [30:28]..[3:1] plus
// one final bit — 11 block-wide reduces instead of 31 (the serial barrier
// chain was the tail's floor; VALUBusy was 5%, so extra compares are free).
// Invariant: count(x >= float(lo)) >= k. Converges to the exact k-th-largest
// bit pattern (same result as 31-step bisection; exact tie handling kept).
// ---------------------------------------------------------------------------
__global__ __launch_bounds__(256) void k_neg(const float* __restrict__ lc,
                                             const float* __restrict__ part_loc,
                                             const float* __restrict__ part_nll,
                                             const int* __restrict__ part_np,
                                             const int* __restrict__ fix_np,
                                             const float* __restrict__ fix_nll,
                                             const float* __restrict__ fix_loc,
                                             float* __restrict__ negsum,
                                             int* __restrict__ done,
                                             float* __restrict__ out) {
    const int b = blockIdx.x;
    const int tid = threadIdx.x;
    const int lane = tid & 63, wid = tid >> 6;
    __shared__ int redc[2][4][8];
    __shared__ float redf[4], redf2[4];
    __shared__ int redi[4];
    __shared__ int np_sh, islast;

    const int NV = Pn / 4;  // 2183 float4s exactly
    const float4* src = reinterpret_cast<const float4*>(lc + (size_t)b * Pn);
    const float4 sent = make_float4(-1.0f, -1.0f, -1.0f, -1.0f);
    float4 rr[12];
#pragma unroll
    for (int j = 0; j < 12; ++j) {
        const int i = tid + 256 * j;
        rr[j] = (i < NV) ? src[i] : sent;
    }

    if (tid < 64) {
        int npl = (tid < PX) ? part_np[b * PX + tid] : 0;
        npl = wave_sum_i(npl);
        if (tid == 63) np_sh = npl;
    }
    __syncthreads();
    const int k = min(3 * (np_sh + fix_np[b]), Pn - 1);

    unsigned lo = 0u;
    int s = 28;
#pragma unroll 1
    for (int it = 0; it < 10; ++it) {
        float f[7];
#pragma unroll
        for (int t = 0; t < 7; ++t) f[t] = __uint_as_float(lo + ((unsigned)(t + 1) << s));
        int c7[7] = {0, 0, 0, 0, 0, 0, 0};
#pragma unroll
        for (int j = 0; j < 12; ++j) {
#pragma unroll
            for (int t = 0; t < 7; ++t) {
                c7[t] += (rr[j].x >= f[t]) + (rr[j].y >= f[t]) +
                         (rr[j].z >= f[t]) + (rr[j].w >= f[t]);
            }
        }
#pragma unroll
        for (int t = 0; t < 7; ++t) c7[t] = wave_sum_i(c7[t]);  // independent chains
        if (lane == 63) {
#pragma unroll
            for (int t = 0; t < 7; ++t) redc[it & 1][wid][t] = c7[t];
        }
        __syncthreads();
        int tsel = 0;
#pragma unroll
        for (int t = 0; t < 7; ++t) {  // counts non-increasing in t: keep last >= k
            const int tot = redc[it & 1][0][t] + redc[it & 1][1][t] +
                            redc[it & 1][2][t] + redc[it & 1][3][t];
            tsel = (tot >= k) ? (t + 1) : tsel;
        }
        lo += (unsigned)tsel << s;
        s -= 3;
    }
    {   // final bit 0 (parity: last loop iter used redc[1]; redc[0] free)
        const float f0 = __uint_as_float(lo | 1u);
        int c = 0;
#pragma unroll
        for (int j = 0; j < 12; ++j)
            c += (rr[j].x >= f0) + (rr[j].y >= f0) + (rr[j].z >= f0) + (rr[j].w >= f0);
        c = wave_sum_i(c);
        if (lane == 63) redc[0][wid][0] = c;
        __syncthreads();
        const int tot = redc[0][0][0] + redc[0][1][0] + redc[0][2][0] + redc[0][3][0];
        if (tot >= k) lo |= 1u;
    }
    const float v = __uint_as_float(lo);  // exact k-th largest value

    float sm = 0.0f;
    int c = 0;
#pragma unroll
    for (int j = 0; j < 12; ++j) {
        if (rr[j].x > v) { sm += rr[j].x; ++c; }
        if (rr[j].y > v) { sm += rr[j].y; ++c; }
        if (rr[j].z > v) { sm += rr[j].z; ++c; }
        if (rr[j].w > v) { sm += rr[j].w; ++c; }
    }
    sm = wave_sum_f(sm);
    c = wave_sum_i(c);
    if (lane == 63) { redf[wid] = sm; redi[wid] = c; }
    __syncthreads();
    if (tid == 0) {
        const float st = redf[0] + redf[1] + redf[2] + redf[3];
        const int ct = redi[0] + redi[1] + redi[2] + redi[3];
        negsum[b] = st + (float)(k - ct) * v;  // exact tie handling at boundary
        __threadfence();
        islast = (atomicAdd(done, 1) == Bn - 1) ? 1 : 0;
    }
    __syncthreads();
    if (!islast) return;
    __threadfence();  // acquire: other blocks' stores precede their fenced atomics

    // ---- fused final reduce (exactly one block runs this) ----
    float sl = 0.0f, sn = 0.0f;
    int np = 0;
    for (int i = tid; i < Bn * PX; i += 256) {
        sl += part_loc[i];
        sn += part_nll[i];
        np += part_np[i];
    }
    if (tid < Bn) {
        sn += negsum[tid] + fix_nll[tid];
        sl += fix_loc[tid];
        np += fix_np[tid];
    }
    sl = wave_sum_f(sl);
    sn = wave_sum_f(sn);
    np = wave_sum_i(np);
    if (lane == 63) { redf[wid] = sn; redf2[wid] = sl; redi[wid] = np; }
    __syncthreads();
    if (tid == 0) {
        const float fN = (float)(redi[0] + redi[1] + redi[2] + redi[3]);
        out[0] = (redf2[0] + redf2[1] + redf2[2] + redf2[3]) / fN;
        out[1] = (redf[0] + redf[1] + redf[2] + redf[3]) / fN;
    }
}

extern "C" void kernel_launch(void* const* d_in, const int* in_sizes, int n_in,
                              void* d_out, int out_size, void* d_ws, size_t ws_size,
                              hipStream_t stream) {
    const float* conf = (const float*)d_in[0];
    const float* loc = (const float*)d_in[1];
    const float* priors = (const float*)d_in[2];
    const float* labels = (const float*)d_in[3];
    const int* objc = (const int*)d_in[4];
    float* out = (float*)d_out;

    // ws layout: sbp_g[3200] | part_loc/nll/np[2240 each] | negsum[64] |
    //            fix_np[64] | fix_nll[64] | fix_loc[64] | lc[Bn*Pn] | done
    int* sbp_g = (int*)d_ws;
    float* part_loc = (float*)(sbp_g + Bn * NMAXn);
    float* part_nll = part_loc + Bn * PX;
    int* part_np = (int*)(part_nll + Bn * PX);
    float* negsum = (float*)(part_np + Bn * PX);
    int* fix_np = (int*)(negsum + Bn);
    float* fix_nll = (float*)(fix_np + Bn);
    float* fix_loc = fix_nll + Bn;
    float* lc = fix_loc + Bn;
    int* done = (int*)(lc + (size_t)Bn * Pn);

    k_fused<<<Bn * PX + Bn * NMAXn, 256, 0, stream>>>(conf, loc, priors, labels, objc,
                                                      lc, part_loc, part_nll, part_np,
                                                      sbp_g);
    k_fix<<<Bn, 64, 0, stream>>>(conf, loc, priors, labels, objc, sbp_g, lc,
                                 fix_np, fix_nll, fix_loc, done);
    k_neg<<<Bn, 256, 0, stream>>>(lc, part_loc, part_nll, part_np,
                                  fix_np, fix_nll, fix_loc, negsum, done, out);
}

// Round 19
// 68.070 us; speedup vs baseline: 1.1231x; 1.1231x over previous
//
#include <hip/hip_runtime.h>
#include <math.h>

#define Bn 64
#define Pn 8732
#define Cn 21
#define NMAXn 50
#define PX 35  // ceil(Pn/256)

// ---------------- DPP wave64 reduces (VALU pipe, not LDS) -------------------
template <int C>
__device__ __forceinline__ float dppf(float x) {
    return __int_as_float(__builtin_amdgcn_update_dpp(0, __float_as_int(x), C, 0xf, 0xf, true));
}
template <int C>
__device__ __forceinline__ int dppi(int x) {
    return __builtin_amdgcn_update_dpp(0, x, C, 0xf, 0xf, true);
}
__device__ __forceinline__ float wave_sum_f(float x) {
    x += dppf<0x111>(x); x += dppf<0x112>(x); x += dppf<0x114>(x);
    x += dppf<0x118>(x); x += dppf<0x142>(x); x += dppf<0x143>(x);
    return x;  // lane 63
}
__device__ __forceinline__ int wave_sum_i(int x) {
    x += dppi<0x111>(x); x += dppi<0x112>(x); x += dppi<0x114>(x);
    x += dppi<0x118>(x); x += dppi<0x142>(x); x += dppi<0x143>(x);
    return x;  // lane 63
}

__device__ __forceinline__ float smoothl1_enc(const float4 l, const float4 pr,
                                              float gx0, float gy0, float gx1, float gy1) {
    const float tx = ((gx0 + gx1) * 0.5f - pr.x) / (0.1f * pr.z);
    const float ty = ((gy0 + gy1) * 0.5f - pr.y) / (0.1f * pr.w);
    const float tw = __logf((gx1 - gx0) / pr.z) * 5.0f;  // /0.2
    const float th = __logf((gy1 - gy0) / pr.w) * 5.0f;
    float s = 0.0f, d;
    d = fabsf(l.x - tx); s += (d < 1.0f) ? 0.5f * d * d : d - 0.5f;
    d = fabsf(l.y - ty); s += (d < 1.0f) ? 0.5f * d * d : d - 0.5f;
    d = fabsf(l.z - tw); s += (d < 1.0f) ? 0.5f * d * d : d - 0.5f;
    d = fabsf(l.w - th); s += (d < 1.0f) ? 0.5f * d * d : d - 0.5f;
    return s;
}

// IoU numerator/denominator (no divide). All >= 0.
#define IOU_IU(gx0, gy0, gx1, gy1, qx0, qy0, qx1, qy1, qarea, I, U)            \
    {                                                                          \
        const float lx = fmaxf(gx0, qx0), ly = fmaxf(gy0, qy0);                \
        const float rx = fminf(gx1, qx1), ry = fminf(gy1, qy1);                \
        const float w = fmaxf(rx - lx, 0.0f), h = fmaxf(ry - ly, 0.0f);        \
        I = w * h;                                                             \
        U = (gx1 - gx0) * (gy1 - gy0) + qarea - I;                             \
    }

// ---------------------------------------------------------------------------
// K1, two roles in one dispatch. Division-free cross-mult comparator.
// Role A: QUAD-tracker GT loop (chain ~25 -> ~6; 4 independent IoU bodies per
// iteration fill the compare-chain latency). Combine: product tie -> min idx.
// Role B: dual-tracker prior loop (R16-identical).
// ---------------------------------------------------------------------------
__global__ __launch_bounds__(256) void k_fused(const float* __restrict__ conf,
                                               const float* __restrict__ loc,
                                               const float* __restrict__ priors,
                                               const float* __restrict__ labels,
                                               const int* __restrict__ objc,
                                               float* __restrict__ lc,
                                               float* __restrict__ part_loc,
                                               float* __restrict__ part_nll,
                                               int* __restrict__ part_np,
                                               int* __restrict__ sbp_g) {
    const int bx = blockIdx.x;
    const int tid = threadIdx.x;
    const int lane = tid & 63, wid = tid >> 6;

    __shared__ float sconf[256 * Cn];  // 21504 B (role A)
    __shared__ float lab[NMAXn * 5];
    __shared__ float rl[4], rn[4];
    __shared__ int rp[4];
    __shared__ float wkI[4], wkU[4];   // role B
    __shared__ int wkP[4];

    if (bx < Bn * PX) {
        // ================= Role A: match + main =================
        const int b = bx / PX;
        const int px = bx % PX;
        const int p0 = px * 256;
        const int rows = min(256, Pn - p0);
        const int cnt = objc[b];                  // uniform -> scalar
        const float* lb = labels + b * NMAXn * 5;

        const float4* src = reinterpret_cast<const float4*>(conf + ((size_t)b * Pn + p0) * Cn);
        const int n4 = rows * Cn / 4;  // rows*21 divisible by 4 for rows in {256,28}
        for (int i = tid; i < n4; i += 256) reinterpret_cast<float4*>(sconf)[i] = src[i];
        for (int i = tid; i < NMAXn * 5; i += 256) lab[i] = labels[b * NMAXn * 5 + i];

        const int p = p0 + tid;
        const int pcl = (p < Pn) ? p : (Pn - 1);
        const float4 pr = reinterpret_cast<const float4*>(priors)[pcl];
        const float px0 = pr.x - 0.5f * pr.z, py0 = pr.y - 0.5f * pr.w;
        const float px1 = pr.x + 0.5f * pr.z, py1 = pr.y + 0.5f * pr.w;
        const float parea = (px1 - px0) * (py1 - py0);
        // quad trackers: t_j owns indices n === j (mod 4). Neutral (0,1) loses
        // to any I>0; all-zero ties resolve to idx 0 at combine (= reference).
        float tI0 = 0.0f, tU0 = 1.0f, tI1 = 0.0f, tU1 = 1.0f;
        float tI2 = 0.0f, tU2 = 1.0f, tI3 = 0.0f, tU3 = 1.0f;
        int tx0 = 0, tx1 = 1, tx2 = 2, tx3 = 3;
        int n = 0;
        for (; n + 3 < cnt; n += 4) {
            float I0, U0, I1, U1, I2, U2, I3, U3;
            IOU_IU(lb[n * 5 + 0], lb[n * 5 + 1], lb[n * 5 + 2], lb[n * 5 + 3],
                   px0, py0, px1, py1, parea, I0, U0);
            IOU_IU(lb[(n + 1) * 5 + 0], lb[(n + 1) * 5 + 1], lb[(n + 1) * 5 + 2],
                   lb[(n + 1) * 5 + 3], px0, py0, px1, py1, parea, I1, U1);
            IOU_IU(lb[(n + 2) * 5 + 0], lb[(n + 2) * 5 + 1], lb[(n + 2) * 5 + 2],
                   lb[(n + 2) * 5 + 3], px0, py0, px1, py1, parea, I2, U2);
            IOU_IU(lb[(n + 3) * 5 + 0], lb[(n + 3) * 5 + 1], lb[(n + 3) * 5 + 2],
                   lb[(n + 3) * 5 + 3], px0, py0, px1, py1, parea, I3, U3);
            if (I0 * tU0 > tI0 * U0) { tI0 = I0; tU0 = U0; tx0 = n; }
            if (I1 * tU1 > tI1 * U1) { tI1 = I1; tU1 = U1; tx1 = n + 1; }
            if (I2 * tU2 > tI2 * U2) { tI2 = I2; tU2 = U2; tx2 = n + 2; }
            if (I3 * tU3 > tI3 * U3) { tI3 = I3; tU3 = U3; tx3 = n + 3; }
        }
        for (; n < cnt; ++n) {  // tail (<=3) -> t0 (index order preserved by combine)
            float I0, U0;
            IOU_IU(lb[n * 5 + 0], lb[n * 5 + 1], lb[n * 5 + 2], lb[n * 5 + 3],
                   px0, py0, px1, py1, parea, I0, U0);
            if (I0 * tU0 > tI0 * U0) { tI0 = I0; tU0 = U0; tx0 = n; }
        }
        float bI0, bU0;
        int bx0;
        {   // combine 4 trackers: product tie -> min index (first occurrence)
            float aI = tI0, aU = tU0;
            int ax = tx0;
            {
                const float a = tI1 * aU, c = aI * tU1;
                if (a > c || (a == c && tx1 < ax)) { aI = tI1; aU = tU1; ax = tx1; }
            }
            float bI_ = tI2, bU_ = tU2;
            int bx_ = tx2;
            {
                const float a = tI3 * bU_, c = bI_ * tU3;
                if (a > c || (a == c && tx3 < bx_)) { bI_ = tI3; bU_ = tU3; bx_ = tx3; }
            }
            {
                const float a = bI_ * aU, c = aI * bU_;
                if (a > c || (a == c && bx_ < ax)) { aI = bI_; aU = bU_; ax = bx_; }
            }
            bI0 = aI; bU0 = aU; bx0 = ax;
        }
        __syncthreads();  // sconf, lab ready

        float my_loc = 0.0f, my_nll = 0.0f;
        int my_np = 0;
        if (tid < rows) {
            const size_t gi = (size_t)b * Pn + p;
            const int ct = (2.0f * bI0 >= bU0) ? ((int)lab[bx0 * 5 + 4] + 1) : 0;
            const float* row = sconf + tid * Cn;  // stride 21: odd -> conflict-benign
            float m = row[0];
#pragma unroll
            for (int j = 1; j < Cn; ++j) m = fmaxf(m, row[j]);
            float s2 = 0.0f;
#pragma unroll
            for (int j = 0; j < Cn; ++j) s2 += __expf(row[j] - m);
            const float nll = __logf(s2) + m - row[ct];
            if (ct > 0) {
                lc[gi] = 0.0f;
                my_np = 1;
                my_nll = nll;
                const float4 l = reinterpret_cast<const float4*>(loc)[gi];
                my_loc = smoothl1_enc(l, pr, lab[bx0 * 5 + 0], lab[bx0 * 5 + 1],
                                      lab[bx0 * 5 + 2], lab[bx0 * 5 + 3]);
            } else {
                lc[gi] = nll;
            }
        }
        my_loc = wave_sum_f(my_loc);
        my_nll = wave_sum_f(my_nll);
        my_np = wave_sum_i(my_np);
        if (lane == 63) { rl[wid] = my_loc; rn[wid] = my_nll; rp[wid] = my_np; }
        __syncthreads();
        if (tid == 0) {
            const int g = b * PX + px;
            part_loc[g] = rl[0] + rl[1] + rl[2] + rl[3];
            part_nll[g] = rn[0] + rn[1] + rn[2] + rn[3];
            part_np[g] = rp[0] + rp[1] + rp[2] + rp[3];
        }
    } else {
        // ================= Role B: block-per-GT best-prior =================
        const int idx = bx - Bn * PX;
        const int b = idx / NMAXn;
        const int n = idx % NMAXn;
        if (n >= objc[b]) return;  // uniform per block
        const float* lbp = labels + (b * NMAXn + n) * 5;
        const float gx0 = lbp[0], gy0 = lbp[1], gx1 = lbp[2], gy1 = lbp[3];
        float bI0, bU0, bI1, bU1;
        int bp0, bp1;
        {
            const float4 pr = reinterpret_cast<const float4*>(priors)[tid];
            const float qx0 = pr.x - 0.5f * pr.z, qy0 = pr.y - 0.5f * pr.w;
            const float qx1 = pr.x + 0.5f * pr.z, qy1 = pr.y + 0.5f * pr.w;
            IOU_IU(gx0, gy0, gx1, gy1, qx0, qy0, qx1, qy1,
                   (qx1 - qx0) * (qy1 - qy0), bI0, bU0);
            bp0 = tid;
        }
        {
            const float4 pr = reinterpret_cast<const float4*>(priors)[tid + 256];
            const float qx0 = pr.x - 0.5f * pr.z, qy0 = pr.y - 0.5f * pr.w;
            const float qx1 = pr.x + 0.5f * pr.z, qy1 = pr.y + 0.5f * pr.w;
            IOU_IU(gx0, gy0, gx1, gy1, qx0, qy0, qx1, qy1,
                   (qx1 - qx0) * (qy1 - qy0), bI1, bU1);
            bp1 = tid + 256;
        }
        int j = 2;
        for (; j + 1 < PX; j += 2) {  // j <= 33: p <= 8703 < Pn, no guard
            const int pA = tid + 256 * j, pB = pA + 256;
            float IA, UA, IB, UB;
            {
                const float4 pr = reinterpret_cast<const float4*>(priors)[pA];
                const float qx0 = pr.x - 0.5f * pr.z, qy0 = pr.y - 0.5f * pr.w;
                const float qx1 = pr.x + 0.5f * pr.z, qy1 = pr.y + 0.5f * pr.w;
                IOU_IU(gx0, gy0, gx1, gy1, qx0, qy0, qx1, qy1,
                       (qx1 - qx0) * (qy1 - qy0), IA, UA);
            }
            {
                const float4 pr = reinterpret_cast<const float4*>(priors)[pB];
                const float qx0 = pr.x - 0.5f * pr.z, qy0 = pr.y - 0.5f * pr.w;
                const float qx1 = pr.x + 0.5f * pr.z, qy1 = pr.y + 0.5f * pr.w;
                IOU_IU(gx0, gy0, gx1, gy1, qx0, qy0, qx1, qy1,
                       (qx1 - qx0) * (qy1 - qy0), IB, UB);
            }
            if (IA * bU0 > bI0 * UA) { bI0 = IA; bU0 = UA; bp0 = pA; }
            if (IB * bU1 > bI1 * UB) { bI1 = IB; bU1 = UB; bp1 = pB; }
        }
        {   // tail j = 34 (guarded)
            const int pA = tid + 256 * 34;
            if (pA < Pn) {
                const float4 pr = reinterpret_cast<const float4*>(priors)[pA];
                const float qx0 = pr.x - 0.5f * pr.z, qy0 = pr.y - 0.5f * pr.w;
                const float qx1 = pr.x + 0.5f * pr.z, qy1 = pr.y + 0.5f * pr.w;
                float IA, UA;
                IOU_IU(gx0, gy0, gx1, gy1, qx0, qy0, qx1, qy1,
                       (qx1 - qx0) * (qy1 - qy0), IA, UA);
                if (IA * bU0 > bI0 * UA) { bI0 = IA; bU0 = UA; bp0 = pA; }
            }
        }
        {   // combine trackers: product tie -> min p
            const float a = bI1 * bU0, c = bI0 * bU1;
            if (a > c || (a == c && bp1 < bp0)) { bI0 = bI1; bU0 = bU1; bp0 = bp1; }
        }
        for (int off = 32; off > 0; off >>= 1) {
            const float oI = __shfl_down(bI0, off);
            const float oU = __shfl_down(bU0, off);
            const int op = __shfl_down(bp0, off);
            const float a = oI * bU0, c = bI0 * oU;
            if (a > c || (a == c && op < bp0)) { bI0 = oI; bU0 = oU; bp0 = op; }
        }
        if (lane == 0) { wkI[wid] = bI0; wkU[wid] = bU0; wkP[wid] = bp0; }
        __syncthreads();
        if (tid == 0) {
            float cI = wkI[0], cU = wkU[0];
            int cp = wkP[0];
#pragma unroll
            for (int w = 1; w < 4; ++w) {
                const float a = wkI[w] * cU, c = cI * wkU[w];
                if (a > c || (a == c && wkP[w] < cp)) { cI = wkI[w]; cU = wkU[w]; cp = wkP[w]; }
            }
            sbp_g[b * NMAXn + n] = cp;
        }
    }
}

// ---------------------------------------------------------------------------
// K2 fixup (one wave per batch, separate kernel — R16-identical).
// ---------------------------------------------------------------------------
__global__ __launch_bounds__(64) void k_fix(const float* __restrict__ conf,
                                            const float* __restrict__ loc,
                                            const float* __restrict__ priors,
                                            const float* __restrict__ labels,
                                            const int* __restrict__ objc,
                                            const int* __restrict__ sbp_g,
                                            float* __restrict__ lc,
                                            int* __restrict__ fix_np,
                                            float* __restrict__ fix_nll,
                                            float* __restrict__ fix_loc,
                                            int* __restrict__ done) {
    __shared__ int sbp[NMAXn];
    __shared__ float lab[NMAXn * 5];
    const int b = blockIdx.x;
    const int tid = threadIdx.x;  // one wave
    if (b == 0 && tid == 0) *done = 0;
    const int cnt = objc[b];
    for (int i = tid; i < NMAXn * 5; i += 64) lab[i] = labels[b * NMAXn * 5 + i];
    if (tid < cnt) sbp[tid] = sbp_g[b * NMAXn + tid];
    __syncthreads();
    bool win = false;
    if (tid < cnt) {
        const int myp = sbp[tid];
        win = true;
        for (int n2 = tid + 1; n2 < cnt; ++n2) win = win && (sbp[n2] != myp);  // last n wins
    }
    float dnll = 0.0f, dloc = 0.0f;
    int dnp = 0;
    if (win) {
        const int pp = sbp[tid];
        const float4 prf = reinterpret_cast<const float4*>(priors)[pp];
        const float qx0 = prf.x - 0.5f * prf.z, qy0 = prf.y - 0.5f * prf.w;
        const float qx1 = prf.x + 0.5f * prf.z, qy1 = prf.y + 0.5f * prf.w;
        const float qarea = (qx1 - qx0) * (qy1 - qy0);
        float bI = 0.0f, bU = 1.0f;
        int bidx2 = 0;
        for (int n2 = 0; n2 < cnt; ++n2) {  // sequential == quad-tracker combined order
            float I, U;
            IOU_IU(lab[n2 * 5 + 0], lab[n2 * 5 + 1], lab[n2 * 5 + 2],
                   lab[n2 * 5 + 3], qx0, qy0, qx1, qy1, qarea, I, U);
            if (I * bU > bI * U) { bI = I; bU = U; bidx2 = n2; }
        }
        const float* rowg = conf + ((size_t)b * Pn + pp) * Cn;
        float m2 = rowg[0];
#pragma unroll
        for (int j = 1; j < Cn; ++j) m2 = fmaxf(m2, rowg[j]);
        float ss = 0.0f;
#pragma unroll
        for (int j = 0; j < Cn; ++j) ss += __expf(rowg[j] - m2);
        const float lse = __logf(ss) + m2;
        const int ctn = (int)lab[tid * 5 + 4] + 1;
        const float4 lv = reinterpret_cast<const float4*>(loc)[(size_t)b * Pn + pp];
        dnll = lse - rowg[ctn];
        dloc = smoothl1_enc(lv, prf, lab[tid * 5 + 0], lab[tid * 5 + 1],
                            lab[tid * 5 + 2], lab[tid * 5 + 3]);
        dnp = 1;
        if (2.0f * bI >= bU) {  // old was positive: subtract its old contribution
            const int cto = (int)lab[bidx2 * 5 + 4] + 1;
            dnll -= (lse - rowg[cto]);
            dloc -= smoothl1_enc(lv, prf, lab[bidx2 * 5 + 0], lab[bidx2 * 5 + 1],
                                 lab[bidx2 * 5 + 2], lab[bidx2 * 5 + 3]);
            dnp = 0;
        }
        lc[(size_t)b * Pn + pp] = 0.0f;  // forced => positive => not a mining candidate
    }
    dnll = wave_sum_f(dnll);
    dloc = wave_sum_f(dloc);
    dnp = wave_sum_i(dnp);
    if (tid == 63) {
        fix_nll[b] = dnll;
        fix_loc[b] = dloc;
        fix_np[b] = dnp;
    }
}

// ---------------------------------------------------------------------------
// K3: per-batch hard-negative top-k sum (R16-identical: 31-iter binary
// bisection, 256 threads x 12 float4 registers, DPP reduces, fused final
// reduce via done counter). Proven non-spilling configuration.
// ---------------------------------------------------------------------------
__global__ __launch_bounds__(256) void k_neg(const float* __restrict__ lc,
                                             const float* __restrict__ part_loc,
                                             const float* __restrict__ part_nll,
                                             const int* __restrict__ part_np,
                                             const int* __restrict__ fix_np,
                                             const float* __restrict__ fix_nll,
                                             const float* __restrict__ fix_loc,
                                             float* __restrict__ negsum,
                                             int* __restrict__ done,
                                             float* __restrict__ out) {
    const int b = blockIdx.x;
    const int tid = threadIdx.x;
    const int lane = tid & 63, wid = tid >> 6;
    __shared__ int redc[2][4];
    __shared__ float redf[4], redf2[4];
    __shared__ int redi[4];
    __shared__ int np_sh, islast;

    const int NV = Pn / 4;  // 2183 float4s exactly
    const float4* src = reinterpret_cast<const float4*>(lc + (size_t)b * Pn);
    const float4 sent = make_float4(-1.0f, -1.0f, -1.0f, -1.0f);
    float4 rr[12];
#pragma unroll
    for (int j = 0; j < 12; ++j) {
        const int i = tid + 256 * j;
        rr[j] = (i < NV) ? src[i] : sent;
    }

    if (tid < 64) {
        int npl = (tid < PX) ? part_np[b * PX + tid] : 0;
        npl = wave_sum_i(npl);
        if (tid == 63) np_sh = npl;
    }
    __syncthreads();
    const int k = min(3 * (np_sh + fix_np[b]), Pn - 1);

    unsigned lo = 0u, hi = 0x7F800000u;
#pragma unroll 1
    for (int it = 0; it < 31; ++it) {
        const unsigned mid = lo + ((hi - lo) >> 1);
        const float fm = __uint_as_float(mid);  // fm >= 0: sentinels never counted
        int c = 0;
#pragma unroll
        for (int j = 0; j < 12; ++j)
            c += (rr[j].x >= fm) + (rr[j].y >= fm) + (rr[j].z >= fm) + (rr[j].w >= fm);
        c = wave_sum_i(c);
        if (lane == 63) redc[it & 1][wid] = c;
        __syncthreads();
        const int tot = redc[it & 1][0] + redc[it & 1][1]
                      + redc[it & 1][2] + redc[it & 1][3];
        if (tot >= k) lo = mid;
        else hi = mid;
    }
    const float v = __uint_as_float(lo);  // exact k-th largest value

    float sm = 0.0f;
    int c = 0;
#pragma unroll
    for (int j = 0; j < 12; ++j) {
        if (rr[j].x > v) { sm += rr[j].x; ++c; }
        if (rr[j].y > v) { sm += rr[j].y; ++c; }
        if (rr[j].z > v) { sm += rr[j].z; ++c; }
        if (rr[j].w > v) { sm += rr[j].w; ++c; }
    }
    sm = wave_sum_f(sm);
    c = wave_sum_i(c);
    if (lane == 63) { redf[wid] = sm; redi[wid] = c; }
    __syncthreads();
    if (tid == 0) {
        const float st = redf[0] + redf[1] + redf[2] + redf[3];
        const int ct = redi[0] + redi[1] + redi[2] + redi[3];
        negsum[b] = st + (float)(k - ct) * v;  // exact tie handling at boundary
        __threadfence();
        islast = (atomicAdd(done, 1) == Bn - 1) ? 1 : 0;
    }
    __syncthreads();
    if (!islast) return;
    __threadfence();  // acquire: other blocks' stores precede their fenced atomics

    // ---- fused final reduce (exactly one block runs this) ----
    float sl = 0.0f, sn = 0.0f;
    int np = 0;
    for (int i = tid; i < Bn * PX; i += 256) {
        sl += part_loc[i];
        sn += part_nll[i];
        np += part_np[i];
    }
    if (tid < Bn) {
        sn += negsum[tid] + fix_nll[tid];
        sl += fix_loc[tid];
        np += fix_np[tid];
    }
    sl = wave_sum_f(sl);
    sn = wave_sum_f(sn);
    np = wave_sum_i(np);
    if (lane == 63) { redf[wid] = sn; redf2[wid] = sl; redi[wid] = np; }
    __syncthreads();
    if (tid == 0) {
        const float fN = (float)(redi[0] + redi[1] + redi[2] + redi[3]);
        out[0] = (redf2[0] + redf2[1] + redf2[2] + redf2[3]) / fN;
        out[1] = (redf[0] + redf[1] + redf[2] + redf[3]) / fN;
    }
}

extern "C" void kernel_launch(void* const* d_in, const int* in_sizes, int n_in,
                              void* d_out, int out_size, void* d_ws, size_t ws_size,
                              hipStream_t stream) {
    const float* conf = (const float*)d_in[0];
    const float* loc = (const float*)d_in[1];
    const float* priors = (const float*)d_in[2];
    const float* labels = (const float*)d_in[3];
    const int* objc = (const int*)d_in[4];
    float* out = (float*)d_out;

    // ws layout: sbp_g[3200] | part_loc/nll/np[2240 each] | negsum[64] |
    //            fix_np[64] | fix_nll[64] | fix_loc[64] | lc[Bn*Pn] | done
    int* sbp_g = (int*)d_ws;
    float* part_loc = (float*)(sbp_g + Bn * NMAXn);
    float* part_nll = part_loc + Bn * PX;
    int* part_np = (int*)(part_nll + Bn * PX);
    float* negsum = (float*)(part_np + Bn * PX);
    int* fix_np = (int*)(negsum + Bn);
    float* fix_nll = (float*)(fix_np + Bn);
    float* fix_loc = fix_nll + Bn;
    float* lc = fix_loc + Bn;
    int* done = (int*)(lc + (size_t)Bn * Pn);

    k_fused<<<Bn * PX + Bn * NMAXn, 256, 0, stream>>>(conf, loc, priors, labels, objc,
                                                      lc, part_loc, part_nll, part_np,
                                                      sbp_g);
    k_fix<<<Bn, 64, 0, stream>>>(conf, loc, priors, labels, objc, sbp_g, lc,
                                 fix_np, fix_nll, fix_loc, done);
    k_neg<<<Bn, 256, 0, stream>>>(lc, part_loc, part_nll, part_np,
                                  fix_np, fix_nll, fix_loc, negsum, done, out);
}